// Round 4
// baseline (672.926 us; speedup 1.0000x reference)
//
#include <hip/hip_runtime.h>
#include <stdint.h>

// ---------------------------------------------------------------------------
// MLA attention, MI355X gfx950.
// Shapes: B=2 S=2048 D=2048 H=16 HD=128 ND=64 RD=64 R=512
// ABI (established rounds 1-3): all 7 inputs fp32, output fp32.
// Internal compute: bf16 intermediates, fp32 MFMA accumulation.
// ---------------------------------------------------------------------------

typedef unsigned short u16;
typedef __bf16 bf16x8 __attribute__((ext_vector_type(8)));
typedef float f32x4 __attribute__((ext_vector_type(4)));

__device__ __forceinline__ float bf2f(u16 u) {
    union { unsigned int i; float f; } x; x.i = ((unsigned int)u) << 16; return x.f;
}
__device__ __forceinline__ u16 f2bf(float f) {
    union { float f; unsigned int i; } x; x.f = f;
    unsigned int r = x.i + 0x7fffu + ((x.i >> 16) & 1u);   // RNE, finite inputs only
    return (u16)(r >> 16);
}
__device__ __forceinline__ void store_c(u16* p, float v)  { *p = f2bf(v); }
__device__ __forceinline__ void store_c(float* p, float v){ *p = v; }

#define GLOBAL_AS __attribute__((address_space(1)))
#define LDS_AS    __attribute__((address_space(3)))
// async global->LDS, 16B per lane. LDS dest must be wave-uniform base + lane*16.
__device__ __forceinline__ void gl_lds16(const void* g, void* l) {
    __builtin_amdgcn_global_load_lds((GLOBAL_AS const void*)g, (LDS_AS void*)l, 16, 0, 0);
}

// ---------------------------------------------------------------------------
// fp32 -> bf16 conversion, 8 elements/thread.
// ---------------------------------------------------------------------------
__global__ void convert_in(const float* __restrict__ src, u16* __restrict__ dst,
                           int n8) {
    int i = blockIdx.x * 256 + threadIdx.x;
    if (i >= n8) return;
    const float4* s = (const float4*)src;
    float4 v0 = s[2*i], v1 = s[2*i + 1];
    union { u16 u[8]; uint4 v; } o;
    o.u[0] = f2bf(v0.x); o.u[1] = f2bf(v0.y); o.u[2] = f2bf(v0.z); o.u[3] = f2bf(v0.w);
    o.u[4] = f2bf(v1.x); o.u[5] = f2bf(v1.y); o.u[6] = f2bf(v1.z); o.u[7] = f2bf(v1.w);
    *((uint4*)(dst + 8*i)) = o.v;
}

// ---------------------------------------------------------------------------
// GEMM: C[m][n] = sum_k A[m][k] * W[n][k]   (A: MxK, W: NxK, row-major, bf16)
// m97-style: BK=32, wave = 64x64 via 4x4 grid of 16x16x32 MFMA,
// global_load_lds width-16 staging. M%BM==0, N%BN==0, K%32==0 assumed.
// CT = u16 (bf16 store) or float (fp32 store).
// ---------------------------------------------------------------------------
template<int BM, int BN, typename CT>
__global__ __launch_bounds__((BM/64)*(BN/64)*64)
void gemm_bt(const u16* __restrict__ A, const u16* __restrict__ W,
             CT* __restrict__ C, int M, int N, int K) {
    constexpr int BK = 32;
    constexpr int NWAVE = (BM/64)*(BN/64);
    constexpr int NT = NWAVE * 64;
    __shared__ u16 As[BM*BK];
    __shared__ u16 Bs[BN*BK];
    const int tid  = threadIdx.x;
    const int lane = tid & 63, l15 = lane & 15, quad = lane >> 4;
    const int wave = tid >> 6;
    const int wm = wave % (BM/64);
    const int wn = wave / (BM/64);
    const int bm = blockIdx.y * BM;
    const int bn = blockIdx.x * BN;

    const f32x4 fzero = {0.f, 0.f, 0.f, 0.f};
    f32x4 acc[4][4];
    #pragma unroll
    for (int i = 0; i < 4; ++i)
        #pragma unroll
        for (int j = 0; j < 4; ++j) acc[i][j] = fzero;

    const size_t Kb = (size_t)K * 2;   // row stride in bytes

    for (int k0 = 0; k0 < K; k0 += BK) {
        #pragma unroll
        for (int i = 0; i < (BM*64)/(NT*16); ++i) {
            int o = (tid + i*NT) * 16;
            int row = o >> 6, colb = o & 63;
            gl_lds16((const char*)A + (size_t)(bm + row)*Kb + (size_t)k0*2 + colb,
                     (char*)As + o);
        }
        #pragma unroll
        for (int i = 0; i < (BN*64)/(NT*16); ++i) {
            int o = (tid + i*NT) * 16;
            int row = o >> 6, colb = o & 63;
            gl_lds16((const char*)W + (size_t)(bn + row)*Kb + (size_t)k0*2 + colb,
                     (char*)Bs + o);
        }
        __syncthreads();

        bf16x8 af[4], bfv[4];
        #pragma unroll
        for (int mt = 0; mt < 4; ++mt)
            af[mt] = *reinterpret_cast<const bf16x8*>(&As[(wm*64 + mt*16 + l15)*BK + quad*8]);
        #pragma unroll
        for (int nt = 0; nt < 4; ++nt)
            bfv[nt] = *reinterpret_cast<const bf16x8*>(&Bs[(wn*64 + nt*16 + l15)*BK + quad*8]);
        #pragma unroll
        for (int mt = 0; mt < 4; ++mt)
            #pragma unroll
            for (int nt = 0; nt < 4; ++nt)
                acc[mt][nt] = __builtin_amdgcn_mfma_f32_16x16x32_bf16(
                    af[mt], bfv[nt], acc[mt][nt], 0, 0, 0);
        __syncthreads();
    }

    // epilogue: C/D layout col=lane&15, row=quad*4+reg (m89/m91 verified)
    #pragma unroll
    for (int mt = 0; mt < 4; ++mt)
        #pragma unroll
        for (int nt = 0; nt < 4; ++nt)
            #pragma unroll
            for (int r = 0; r < 4; ++r) {
                int gm = bm + wm*64 + mt*16 + quad*4 + r;
                int gn = bn + wn*64 + nt*16 + l15;
                store_c(&C[(size_t)gm * N + gn], acc[mt][nt][r]);
            }
}

// ---------------------------------------------------------------------------
// In-place RoPE on bf16 buffer. One thread per (row, pair i of 32).
// pos = (row / pos_div) % 2048.  out[2i]   = x[2i]*cos - x[2i+1]*sin
//                                out[2i+1] = x[2i+1]*cos + x[2i]*sin
// ---------------------------------------------------------------------------
__global__ void rope_kernel(u16* buf, int total_pairs, int row_stride,
                            int col_off, int pos_div) {
    int idx = blockIdx.x * 256 + threadIdx.x;
    if (idx >= total_pairs) return;
    int row = idx >> 5;
    int i   = idx & 31;
    int pos = (row / pos_div) & 2047;                // % S
    float freq = powf(10000.0f, -(float)i * (1.0f/32.0f));  // theta^(-2i/64)
    float ang  = (float)pos * freq;
    float s = sinf(ang), c = cosf(ang);              // accurate range reduction
    u16* p = buf + (size_t)row * row_stride + col_off + 2*i;
    float x0 = bf2f(p[0]), x1 = bf2f(p[1]);
    p[0] = f2bf(x0*c - x1*s);
    p[1] = f2bf(x1*c + x0*s);
}

// ---------------------------------------------------------------------------
// Flash-style causal attention, v2.
// grid = (16 q-tiles of 128, B*H), qt reversed (long blocks first).
// block = 256 (4 waves); wave owns 32 q-rows (2 m-tiles of 16).
// K_eff = [k_nope(64) | k_rope(64)] staged swizzled via global_load_lds.
// V staged TRANSPOSED (Vt[d][kv], stride 68) via register round-trip:
//   per-lane global bf16x8 load (row = lane) + 8 conflict-free ds_write_b16.
// PV B-frags are then contiguous ds_read_b128 (l15 stride 34 words = 2 banks).
// P goes C-layout -> wave-private LDS (stride 68) -> A-layout (m120 pattern).
// Q A-frags live in registers (no Qs LDS). LDS total = 50 KB.
// ---------------------------------------------------------------------------
__global__ __launch_bounds__(256)
void attn_kernel(const u16* __restrict__ Q, const u16* __restrict__ KN,
                 const u16* __restrict__ KR, const u16* __restrict__ V,
                 u16* __restrict__ Oout) {
    constexpr int S = 2048;
    const int qt = 15 - (int)blockIdx.x;     // reversed: 32-iter blocks first
    const int bh = blockIdx.y;
    const int b = bh >> 4, h = bh & 15;

    __shared__ u16 Ks[64*128];     // swizzled chunks, 16384 B
    __shared__ u16 Vt[128*68];     // V^T: row=d(128), col=kv(64), 17408 B
    __shared__ u16 Ps[128*68];     // P: row=q-local(128), col=kv(64), 17408 B

    const int tid  = threadIdx.x;
    const int lane = tid & 63, l15 = lane & 15, quad = lane >> 4;
    const int wave = tid >> 6;

    // Q A-frags in registers: A[m=l15][k=quad*8+j], 2 m-tiles x 4 k-steps
    const u16* qbase = Q + ((size_t)(b*S + qt*128) * 2048 + h*128);
    bf16x8 aq[2][4];
    #pragma unroll
    for (int mt = 0; mt < 2; ++mt)
        #pragma unroll
        for (int ks = 0; ks < 4; ++ks)
            aq[mt][ks] = *reinterpret_cast<const bf16x8*>(
                qbase + (size_t)(wave*32 + mt*16 + l15)*2048 + ks*32 + quad*8);

    const f32x4 fzero = {0.f, 0.f, 0.f, 0.f};
    const float NEG = -1e30f;      // mask sentinel: no overflow corner, exp -> 0
    float m_i[2][4], l_i[2][4];
    f32x4 oacc[2][8];
    #pragma unroll
    for (int mt = 0; mt < 2; ++mt) {
        #pragma unroll
        for (int r = 0; r < 4; ++r) { m_i[mt][r] = NEG; l_i[mt][r] = 0.f; }
        #pragma unroll
        for (int i = 0; i < 8; ++i) oacc[mt][i] = fzero;
    }

    const float scale = 0.08838834764831845f;   // 1/sqrt(128)
    const int nkt = 2*qt + 2;

    for (int kt = 0; kt < nkt; ++kt) {
        const char* knb = (const char*)(KN + ((size_t)(b*S + kt*64)*1024 + h*64));
        const char* krb = (const char*)(KR + ((size_t)(b*S + kt*64)*64));
        const u16*  vbp = V + ((size_t)(b*S + kt*64)*2048 + h*128);

        // --- stage K (swizzled, async) ---
        #pragma unroll
        for (int i = 0; i < 4; ++i) {
            int o = (tid + i*256) * 16;
            int row   = o >> 8;
            int c_lds = (o >> 4) & 15;
            int cg    = c_lds ^ (row & 15);     // logical 16B chunk for this slot
            const char* g = (cg < 8) ? (knb + (size_t)row*2048 + cg*16)
                                     : (krb + (size_t)row*128 + (cg - 8)*16);
            gl_lds16(g, (char*)Ks + o);
        }
        // --- stage V transposed: lane owns kv-row = lane, wave owns 32 d-cols ---
        #pragma unroll
        for (int m = 0; m < 4; ++m) {
            union { bf16x8 v; u16 u[8]; } vv;
            vv.v = *reinterpret_cast<const bf16x8*>(
                vbp + (size_t)lane*2048 + wave*32 + m*8);
            #pragma unroll
            for (int j = 0; j < 8; ++j)
                Vt[(wave*32 + m*8 + j)*68 + lane] = vv.u[j];
        }
        __syncthreads();

        // --- per m-tile: S = Q K^T, online softmax, P -> LDS ---
        #pragma unroll
        for (int mt = 0; mt < 2; ++mt) {
            const int qrow0 = qt*128 + wave*32 + mt*16 + quad*4;
            f32x4 sfr[4];
            #pragma unroll
            for (int nt = 0; nt < 4; ++nt) {
                f32x4 s = fzero;
                int n = nt*16 + l15;
                #pragma unroll
                for (int ks = 0; ks < 4; ++ks) {
                    int c = ks*4 + quad;        // logical chunk along k
                    bf16x8 bk = *reinterpret_cast<const bf16x8*>(
                        &Ks[n*128 + ((c ^ l15) * 8)]);
                    s = __builtin_amdgcn_mfma_f32_16x16x32_bf16(aq[mt][ks], bk, s, 0, 0, 0);
                }
                sfr[nt] = s;
            }
            // scale + causal mask
            #pragma unroll
            for (int nt = 0; nt < 4; ++nt) {
                int kg = kt*64 + nt*16 + l15;
                #pragma unroll
                for (int r = 0; r < 4; ++r) {
                    float v = sfr[nt][r] * scale;
                    sfr[nt][r] = (kg <= qrow0 + r) ? v : NEG;
                }
            }
            // row max across the quad's 16 lanes
            float rm[4];
            #pragma unroll
            for (int r = 0; r < 4; ++r)
                rm[r] = fmaxf(fmaxf(sfr[0][r], sfr[1][r]), fmaxf(sfr[2][r], sfr[3][r]));
            #pragma unroll
            for (int off = 1; off < 16; off <<= 1)
                #pragma unroll
                for (int r = 0; r < 4; ++r)
                    rm[r] = fmaxf(rm[r], __shfl_xor(rm[r], off, 64));

            float alpha[4];
            #pragma unroll
            for (int r = 0; r < 4; ++r) {
                float mn = fmaxf(m_i[mt][r], rm[r]);
                alpha[r] = __expf(m_i[mt][r] - mn);   // first tile: exp(-1e30)=0
                m_i[mt][r] = mn;
                l_i[mt][r] *= alpha[r];
            }
            float rs[4] = {0.f, 0.f, 0.f, 0.f};
            float pf[4][4];
            #pragma unroll
            for (int nt = 0; nt < 4; ++nt)
                #pragma unroll
                for (int r = 0; r < 4; ++r) {
                    float p = __expf(sfr[nt][r] - m_i[mt][r]);
                    pf[nt][r] = p;
                    rs[r] += p;
                }
            #pragma unroll
            for (int off = 1; off < 16; off <<= 1)
                #pragma unroll
                for (int r = 0; r < 4; ++r)
                    rs[r] += __shfl_xor(rs[r], off, 64);
            #pragma unroll
            for (int r = 0; r < 4; ++r) l_i[mt][r] += rs[r];
            #pragma unroll
            for (int i = 0; i < 8; ++i)
                #pragma unroll
                for (int r = 0; r < 4; ++r)
                    oacc[mt][i][r] *= alpha[r];

            // P: C-layout -> LDS (wave-private rows, stride 68: conflict-free)
            #pragma unroll
            for (int nt = 0; nt < 4; ++nt)
                #pragma unroll
                for (int r = 0; r < 4; ++r)
                    Ps[(wave*32 + mt*16 + quad*4 + r)*68 + nt*16 + l15] = f2bf(pf[nt][r]);
        }

        // --- O += P V : A-frags from Ps, B-frags = vector reads from Vt ---
        #pragma unroll
        for (int ks = 0; ks < 2; ++ks) {
            bf16x8 pa0 = *reinterpret_cast<const bf16x8*>(
                &Ps[(wave*32 + 0  + l15)*68 + ks*32 + quad*8]);
            bf16x8 pa1 = *reinterpret_cast<const bf16x8*>(
                &Ps[(wave*32 + 16 + l15)*68 + ks*32 + quad*8]);
            #pragma unroll
            for (int ntv = 0; ntv < 8; ++ntv) {
                bf16x8 bv = *reinterpret_cast<const bf16x8*>(
                    &Vt[(ntv*16 + l15)*68 + ks*32 + quad*8]);
                oacc[0][ntv] = __builtin_amdgcn_mfma_f32_16x16x32_bf16(pa0, bv, oacc[0][ntv], 0, 0, 0);
                oacc[1][ntv] = __builtin_amdgcn_mfma_f32_16x16x32_bf16(pa1, bv, oacc[1][ntv], 0, 0, 0);
            }
        }
        __syncthreads();   // before next tile overwrites Ks/Vt
    }

    // epilogue: normalize and write (b, s, h*128+d)
    u16* obase = Oout + ((size_t)(b*S + qt*128) * 2048 + h*128);
    #pragma unroll
    for (int mt = 0; mt < 2; ++mt)
        #pragma unroll
        for (int r = 0; r < 4; ++r) {
            float inv = 1.0f / l_i[mt][r];
            int qrow = wave*32 + mt*16 + quad*4 + r;
            #pragma unroll
            for (int ntv = 0; ntv < 8; ++ntv) {
                int d = ntv*16 + l15;
                obase[(size_t)qrow*2048 + d] = f2bf(oacc[mt][ntv][r] * inv);
            }
        }
}

// ---------------------------------------------------------------------------
// Host launcher. Inputs fp32, output fp32.
// ---------------------------------------------------------------------------
extern "C" void kernel_launch(void* const* d_in, const int* in_sizes, int n_in,
                              void* d_out, int out_size, void* d_ws, size_t ws_size,
                              hipStream_t stream) {
    (void)in_sizes; (void)n_in; (void)out_size; (void)ws_size;
    float* out = (float*)d_out;
    char* ws = (char*)d_ws;

    // workspace layout (bytes) — total ~77.3 MB
    u16* q      = (u16*)(ws);                  // 4096x2048 = 16,777,216 B
    u16* ckv    = (u16*)(ws + 16777216);       // 4096x512     4,194,304 B
    u16* kr     = (u16*)(ws + 20971520);       // 4096x64        524,288 B
    u16* v      = (u16*)(ws + 21495808);       // 4096x2048   16,777,216 B
    u16* xc     = (u16*)(ws + 38273024);       // 4096x2048   16,777,216 B (attn reuses)
    u16* wqc    = (u16*)(ws + 55050240);       // 2048x2048    8,388,608 B (kn reuses)
    u16* kvdc   = (u16*)(ws + 63438848);       // 512x2048     2,097,152 B
    u16* kupc   = (u16*)(ws + 65536000);       // 1024x512     1,048,576 B
    u16* kropec = (u16*)(ws + 66584576);       // 64x2048        262,144 B
    u16* vupc   = (u16*)(ws + 66846720);       // 2048x512     2,097,152 B
    u16* woc    = (u16*)(ws + 68943872);       // 2048x2048    8,388,608 B
    u16* attn   = xc;    // xc dead after the 3 projections
    u16* kn     = wqc;   // wqc dead after q gemm

    // 1) canonicalize all fp32 inputs to bf16 workspace copies
    struct { const void* src; u16* dst; int n; } conv[7] = {
        { d_in[0], xc,     4096*2048 },
        { d_in[1], wqc,    2048*2048 },
        { d_in[2], kvdc,    512*2048 },
        { d_in[3], kupc,   1024*512  },
        { d_in[4], kropec,   64*2048 },
        { d_in[5], vupc,   2048*512  },
        { d_in[6], woc,    2048*2048 },
    };
    for (int i = 0; i < 7; ++i) {
        int n8 = conv[i].n / 8;
        convert_in<<<(n8 + 255)/256, 256, 0, stream>>>((const float*)conv[i].src,
                                                       conv[i].dst, n8);
    }

    // 2) projections (bf16 out)
    gemm_bt<128,128><<<dim3(16, 32), 256, 0, stream>>>(xc, wqc, q, 4096, 2048, 2048);
    gemm_bt<128,128><<<dim3(4, 32), 256, 0, stream>>>(xc, kvdc, ckv, 4096, 512, 2048);
    gemm_bt<128,64><<<dim3(1, 32), 128, 0, stream>>>(xc, kropec, kr, 4096, 64, 2048);

    // 3) RoPE: q rope-half (rows=(b*S+s)*16+h, stride 128, cols 64..127); kr full
    rope_kernel<<<(2097152 + 255)/256, 256, 0, stream>>>(q, 2097152, 128, 64, 16);
    rope_kernel<<<(131072 + 255)/256, 256, 0, stream>>>(kr, 131072, 64, 0, 1);

    // 4) up-projections
    gemm_bt<128,128><<<dim3(8, 32), 256, 0, stream>>>(ckv, kupc, kn, 4096, 1024, 512);
    gemm_bt<128,128><<<dim3(16, 32), 256, 0, stream>>>(ckv, vupc, v, 4096, 2048, 512);

    // 5) attention: grid (16 q-tiles of 128, b*h), qt reversed in-kernel
    attn_kernel<<<dim3(16, 32), 256, 0, stream>>>(q, kn, kr, v, attn);

    // 6) output projection -> fp32 directly into d_out
    gemm_bt<128,128><<<dim3(16, 32), 256, 0, stream>>>(attn, woc, out, 4096, 2048, 2048);
}

// Round 5
// 566.756 us; speedup vs baseline: 1.1873x; 1.1873x over previous
//
#include <hip/hip_runtime.h>
#include <stdint.h>

// ---------------------------------------------------------------------------
// MLA attention, MI355X gfx950.
// Shapes: B=2 S=2048 D=2048 H=16 HD=128 ND=64 RD=64 R=512
// ABI (established rounds 1-3): all 7 inputs fp32, output fp32.
// Internal compute: bf16 intermediates, fp32 MFMA accumulation.
// ---------------------------------------------------------------------------

typedef unsigned short u16;
typedef __bf16 bf16x8 __attribute__((ext_vector_type(8)));
typedef float f32x4 __attribute__((ext_vector_type(4)));

__device__ __forceinline__ float bf2f(u16 u) {
    union { unsigned int i; float f; } x; x.i = ((unsigned int)u) << 16; return x.f;
}
__device__ __forceinline__ u16 f2bf(float f) {
    union { float f; unsigned int i; } x; x.f = f;
    unsigned int r = x.i + 0x7fffu + ((x.i >> 16) & 1u);   // RNE, finite inputs only
    return (u16)(r >> 16);
}
__device__ __forceinline__ void store_c(u16* p, float v)  { *p = f2bf(v); }
__device__ __forceinline__ void store_c(float* p, float v){ *p = v; }

#define GLOBAL_AS __attribute__((address_space(1)))
#define LDS_AS    __attribute__((address_space(3)))
// async global->LDS, 16B per lane. LDS dest must be wave-uniform base + lane*16.
__device__ __forceinline__ void gl_lds16(const void* g, void* l) {
    __builtin_amdgcn_global_load_lds((GLOBAL_AS const void*)g, (LDS_AS void*)l, 16, 0, 0);
}

// ---------------------------------------------------------------------------
// fp32 -> bf16 conversion, 8 elements/thread.
// ---------------------------------------------------------------------------
__global__ void convert_in(const float* __restrict__ src, u16* __restrict__ dst,
                           int n8) {
    int i = blockIdx.x * 256 + threadIdx.x;
    if (i >= n8) return;
    const float4* s = (const float4*)src;
    float4 v0 = s[2*i], v1 = s[2*i + 1];
    union { u16 u[8]; uint4 v; } o;
    o.u[0] = f2bf(v0.x); o.u[1] = f2bf(v0.y); o.u[2] = f2bf(v0.z); o.u[3] = f2bf(v0.w);
    o.u[4] = f2bf(v1.x); o.u[5] = f2bf(v1.y); o.u[6] = f2bf(v1.z); o.u[7] = f2bf(v1.w);
    *((uint4*)(dst + 8*i)) = o.v;
}

// ---------------------------------------------------------------------------
// GEMM: C[m][n] = sum_k A[m][k] * W[n][k]   (A: MxK, W: NxK, row-major, bf16)
// m97-style: BK=32, wave = 64x64 via 4x4 grid of 16x16x32 MFMA,
// global_load_lds width-16 staging. M%BM==0, N%BN==0, K%32==0 assumed.
// CT = u16 (bf16 store) or float (fp32 store).
// ---------------------------------------------------------------------------
template<int BM, int BN, typename CT>
__global__ __launch_bounds__((BM/64)*(BN/64)*64)
void gemm_bt(const u16* __restrict__ A, const u16* __restrict__ W,
             CT* __restrict__ C, int M, int N, int K) {
    constexpr int BK = 32;
    constexpr int NWAVE = (BM/64)*(BN/64);
    constexpr int NT = NWAVE * 64;
    __shared__ u16 As[BM*BK];
    __shared__ u16 Bs[BN*BK];
    const int tid  = threadIdx.x;
    const int lane = tid & 63, l15 = lane & 15, quad = lane >> 4;
    const int wave = tid >> 6;
    const int wm = wave % (BM/64);
    const int wn = wave / (BM/64);
    const int bm = blockIdx.y * BM;
    const int bn = blockIdx.x * BN;

    const f32x4 fzero = {0.f, 0.f, 0.f, 0.f};
    f32x4 acc[4][4];
    #pragma unroll
    for (int i = 0; i < 4; ++i)
        #pragma unroll
        for (int j = 0; j < 4; ++j) acc[i][j] = fzero;

    const size_t Kb = (size_t)K * 2;   // row stride in bytes

    for (int k0 = 0; k0 < K; k0 += BK) {
        #pragma unroll
        for (int i = 0; i < (BM*64)/(NT*16); ++i) {
            int o = (tid + i*NT) * 16;
            int row = o >> 6, colb = o & 63;
            gl_lds16((const char*)A + (size_t)(bm + row)*Kb + (size_t)k0*2 + colb,
                     (char*)As + o);
        }
        #pragma unroll
        for (int i = 0; i < (BN*64)/(NT*16); ++i) {
            int o = (tid + i*NT) * 16;
            int row = o >> 6, colb = o & 63;
            gl_lds16((const char*)W + (size_t)(bn + row)*Kb + (size_t)k0*2 + colb,
                     (char*)Bs + o);
        }
        __syncthreads();

        bf16x8 af[4], bfv[4];
        #pragma unroll
        for (int mt = 0; mt < 4; ++mt)
            af[mt] = *reinterpret_cast<const bf16x8*>(&As[(wm*64 + mt*16 + l15)*BK + quad*8]);
        #pragma unroll
        for (int nt = 0; nt < 4; ++nt)
            bfv[nt] = *reinterpret_cast<const bf16x8*>(&Bs[(wn*64 + nt*16 + l15)*BK + quad*8]);
        #pragma unroll
        for (int mt = 0; mt < 4; ++mt)
            #pragma unroll
            for (int nt = 0; nt < 4; ++nt)
                acc[mt][nt] = __builtin_amdgcn_mfma_f32_16x16x32_bf16(
                    af[mt], bfv[nt], acc[mt][nt], 0, 0, 0);
        __syncthreads();
    }

    // epilogue: C/D layout col=lane&15, row=quad*4+reg (m89/m91 verified)
    #pragma unroll
    for (int mt = 0; mt < 4; ++mt)
        #pragma unroll
        for (int nt = 0; nt < 4; ++nt)
            #pragma unroll
            for (int r = 0; r < 4; ++r) {
                int gm = bm + wm*64 + mt*16 + quad*4 + r;
                int gn = bn + wn*64 + nt*16 + l15;
                store_c(&C[(size_t)gm * N + gn], acc[mt][nt][r]);
            }
}

// ---------------------------------------------------------------------------
// In-place RoPE on bf16 buffer. One thread per (row, pair i of 32).
// pos = (row / pos_div) % 2048.  out[2i]   = x[2i]*cos - x[2i+1]*sin
//                                out[2i+1] = x[2i+1]*cos + x[2i]*sin
// ---------------------------------------------------------------------------
__global__ void rope_kernel(u16* buf, int total_pairs, int row_stride,
                            int col_off, int pos_div) {
    int idx = blockIdx.x * 256 + threadIdx.x;
    if (idx >= total_pairs) return;
    int row = idx >> 5;
    int i   = idx & 31;
    int pos = (row / pos_div) & 2047;                // % S
    float freq = powf(10000.0f, -(float)i * (1.0f/32.0f));  // theta^(-2i/64)
    float ang  = (float)pos * freq;
    float s = sinf(ang), c = cosf(ang);              // accurate range reduction
    u16* p = buf + (size_t)row * row_stride + col_off + 2*i;
    float x0 = bf2f(p[0]), x1 = bf2f(p[1]);
    p[0] = f2bf(x0*c - x1*s);
    p[1] = f2bf(x1*c + x0*s);
}

// ---------------------------------------------------------------------------
// Flash-style causal attention, v3: latency-hiding rewrite.
// grid = (32 q-tiles of 64, B*H), qt reversed (long blocks first).
// block = 256 (4 waves); wave owns 16 q-rows. 12 waves/CU (42.5 KB LDS).
// Staging is SOFTWARE-PIPELINED: K/V for tile kt+1 are loaded into registers
// during compute of tile kt, then dumped to LDS at the top of the next
// iteration (ds_write_b128 / b16) — no global latency inside the barrier pair.
// K keeps the global-source XOR swizzle (QK B-frag reads measured 0-conflict);
// V is stored transposed Vt[d][kv] stride 68; P stride 68 (m120 round-trip).
// ---------------------------------------------------------------------------
__global__ __launch_bounds__(256, 3)
void attn_kernel(const u16* __restrict__ Q, const u16* __restrict__ KN,
                 const u16* __restrict__ KR, const u16* __restrict__ V,
                 u16* __restrict__ Oout) {
    constexpr int S = 2048;
    const int qt = 31 - (int)blockIdx.x;     // reversed: long blocks first
    const int bh = blockIdx.y;
    const int b = bh >> 4, h = bh & 15;

    __shared__ u16 Ks[64*128];     // swizzled chunks (linear), 16384 B
    __shared__ u16 Vt[128*68];     // V^T: row=d(128), col=kv(64)+pad, 17408 B
    __shared__ u16 Ps[64*68];      // P: row=q-local(64), col=kv(64)+pad, 8704 B

    const int tid  = threadIdx.x;
    const int lane = tid & 63, l15 = lane & 15, quad = lane >> 4;
    const int wave = tid >> 6;

    // Q A-frags in registers: A[m=l15][k=quad*8+j], 4 k-steps of 32
    const u16* qbase = Q + ((size_t)(b*S + qt*64) * 2048 + h*128);
    bf16x8 aq[4];
    #pragma unroll
    for (int ks = 0; ks < 4; ++ks)
        aq[ks] = *reinterpret_cast<const bf16x8*>(
            qbase + (size_t)(wave*16 + l15)*2048 + ks*32 + quad*8);

    // K staging source descriptors (swizzle folded into the global address).
    // Thread's chunk i: g = tid + i*256; row = g>>4, c_lds = g&15,
    // cg = c_lds ^ (row&15); cg<8 -> k_nope row, else k_rope row.
    const u16* knb0 = KN + ((size_t)(b*S)*1024 + h*64);
    const u16* krb0 = KR + ((size_t)(b*S)*64);
    const u16* vb0  = V  + ((size_t)(b*S)*2048 + h*128);
    const u16* ksrc[4];
    int kstep[4];
    #pragma unroll
    for (int i = 0; i < 4; ++i) {
        int g = tid + i*256, row = g >> 4, c = g & 15;
        int cg = c ^ (row & 15);
        if (cg < 8) { ksrc[i] = knb0 + (size_t)row*1024 + cg*8;      kstep[i] = 64*1024; }
        else        { ksrc[i] = krb0 + (size_t)row*64 + (cg-8)*8;    kstep[i] = 64*64;   }
    }
    const u16* vsrc = vb0 + (size_t)lane*2048 + wave*32;   // + m*8, step 64*2048/kt

    const int nkt = qt + 1;

    // prefetch tile 0 into registers
    bf16x8 kreg[4], vreg[4];
    #pragma unroll
    for (int i = 0; i < 4; ++i) kreg[i] = *reinterpret_cast<const bf16x8*>(ksrc[i]);
    #pragma unroll
    for (int m = 0; m < 4; ++m) vreg[m] = *reinterpret_cast<const bf16x8*>(vsrc + m*8);

    const f32x4 fzero = {0.f, 0.f, 0.f, 0.f};
    const float NEG = -1e30f;      // mask sentinel: no overflow corner, exp -> 0
    float m_i[4] = {NEG, NEG, NEG, NEG};
    float l_i[4] = {0.f, 0.f, 0.f, 0.f};
    f32x4 oacc[8];
    #pragma unroll
    for (int i = 0; i < 8; ++i) oacc[i] = fzero;

    const float scale = 0.08838834764831845f;   // 1/sqrt(128)
    const int qrow0 = qt*64 + wave*16 + quad*4;

    for (int kt = 0; kt < nkt; ++kt) {
        // --- dump prefetched tile kt to LDS ---
        #pragma unroll
        for (int i = 0; i < 4; ++i)
            *reinterpret_cast<bf16x8*>(&Ks[(tid + i*256) * 8]) = kreg[i];
        #pragma unroll
        for (int m = 0; m < 4; ++m) {
            union { bf16x8 v; u16 u[8]; } vv; vv.v = vreg[m];
            #pragma unroll
            for (int j = 0; j < 8; ++j)
                Vt[(wave*32 + m*8 + j)*68 + lane] = vv.u[j];
        }
        // --- issue prefetch for tile kt+1 (clamped; discarded on last iter) ---
        {
            int ktn = (kt + 1 < nkt) ? kt + 1 : kt;
            #pragma unroll
            for (int i = 0; i < 4; ++i)
                kreg[i] = *reinterpret_cast<const bf16x8*>(ksrc[i] + (size_t)ktn*kstep[i]);
            #pragma unroll
            for (int m = 0; m < 4; ++m)
                vreg[m] = *reinterpret_cast<const bf16x8*>(vsrc + (size_t)ktn*(64*2048) + m*8);
        }
        __syncthreads();   // staging visible to all waves

        // --- S = Q K^T (16 q-rows x 64 kv-cols per wave) ---
        f32x4 sfr[4];
        #pragma unroll
        for (int nt = 0; nt < 4; ++nt) {
            f32x4 s = fzero;
            int n = nt*16 + l15;
            #pragma unroll
            for (int ks = 0; ks < 4; ++ks) {
                int c = ks*4 + quad;            // logical chunk along k
                bf16x8 bk = *reinterpret_cast<const bf16x8*>(&Ks[n*128 + ((c ^ l15) * 8)]);
                s = __builtin_amdgcn_mfma_f32_16x16x32_bf16(aq[ks], bk, s, 0, 0, 0);
            }
            sfr[nt] = s;
        }
        // scale + causal mask
        #pragma unroll
        for (int nt = 0; nt < 4; ++nt) {
            int kg = kt*64 + nt*16 + l15;
            #pragma unroll
            for (int r = 0; r < 4; ++r) {
                float v = sfr[nt][r] * scale;
                sfr[nt][r] = (kg <= qrow0 + r) ? v : NEG;
            }
        }
        // online softmax (rows live across the quad's 16 lanes)
        float rm[4];
        #pragma unroll
        for (int r = 0; r < 4; ++r)
            rm[r] = fmaxf(fmaxf(sfr[0][r], sfr[1][r]), fmaxf(sfr[2][r], sfr[3][r]));
        #pragma unroll
        for (int off = 1; off < 16; off <<= 1)
            #pragma unroll
            for (int r = 0; r < 4; ++r)
                rm[r] = fmaxf(rm[r], __shfl_xor(rm[r], off, 64));

        float alpha[4];
        #pragma unroll
        for (int r = 0; r < 4; ++r) {
            float mn = fmaxf(m_i[r], rm[r]);
            alpha[r] = __expf(m_i[r] - mn);     // first tile: exp(-1e30) = 0
            m_i[r] = mn;
            l_i[r] *= alpha[r];
        }
        float rs[4] = {0.f, 0.f, 0.f, 0.f};
        float pf[4][4];
        #pragma unroll
        for (int nt = 0; nt < 4; ++nt)
            #pragma unroll
            for (int r = 0; r < 4; ++r) {
                float p = __expf(sfr[nt][r] - m_i[r]);
                pf[nt][r] = p;
                rs[r] += p;
            }
        #pragma unroll
        for (int off = 1; off < 16; off <<= 1)
            #pragma unroll
            for (int r = 0; r < 4; ++r)
                rs[r] += __shfl_xor(rs[r], off, 64);
        #pragma unroll
        for (int r = 0; r < 4; ++r) l_i[r] += rs[r];
        #pragma unroll
        for (int i = 0; i < 8; ++i)
            #pragma unroll
            for (int r = 0; r < 4; ++r)
                oacc[i][r] *= alpha[r];

        // P: C-layout -> LDS (wave-private rows, stride 68: conflict-free)
        #pragma unroll
        for (int nt = 0; nt < 4; ++nt)
            #pragma unroll
            for (int r = 0; r < 4; ++r)
                Ps[(wave*16 + quad*4 + r)*68 + nt*16 + l15] = f2bf(pf[nt][r]);

        // --- O += P V : A-frags from Ps, B-frags = vector reads from Vt ---
        #pragma unroll
        for (int ks = 0; ks < 2; ++ks) {
            bf16x8 pa = *reinterpret_cast<const bf16x8*>(
                &Ps[(wave*16 + l15)*68 + ks*32 + quad*8]);
            #pragma unroll
            for (int ntv = 0; ntv < 8; ++ntv) {
                bf16x8 bv = *reinterpret_cast<const bf16x8*>(
                    &Vt[(ntv*16 + l15)*68 + ks*32 + quad*8]);
                oacc[ntv] = __builtin_amdgcn_mfma_f32_16x16x32_bf16(pa, bv, oacc[ntv], 0, 0, 0);
            }
        }
        __syncthreads();   // all waves done reading before next tile's writes
    }

    // epilogue: normalize and write (b, s, h*128+d)
    u16* obase = Oout + ((size_t)(b*S + qt*64) * 2048 + h*128);
    #pragma unroll
    for (int r = 0; r < 4; ++r) {
        float inv = 1.0f / l_i[r];
        int qrow = wave*16 + quad*4 + r;
        #pragma unroll
        for (int ntv = 0; ntv < 8; ++ntv) {
            int d = ntv*16 + l15;
            obase[(size_t)qrow*2048 + d] = f2bf(oacc[ntv][r] * inv);
        }
    }
}

// ---------------------------------------------------------------------------
// Host launcher. Inputs fp32, output fp32.
// ---------------------------------------------------------------------------
extern "C" void kernel_launch(void* const* d_in, const int* in_sizes, int n_in,
                              void* d_out, int out_size, void* d_ws, size_t ws_size,
                              hipStream_t stream) {
    (void)in_sizes; (void)n_in; (void)out_size; (void)ws_size;
    float* out = (float*)d_out;
    char* ws = (char*)d_ws;

    // workspace layout (bytes) — total ~77.3 MB
    u16* q      = (u16*)(ws);                  // 4096x2048 = 16,777,216 B
    u16* ckv    = (u16*)(ws + 16777216);       // 4096x512     4,194,304 B
    u16* kr     = (u16*)(ws + 20971520);       // 4096x64        524,288 B
    u16* v      = (u16*)(ws + 21495808);       // 4096x2048   16,777,216 B
    u16* xc     = (u16*)(ws + 38273024);       // 4096x2048   16,777,216 B (attn reuses)
    u16* wqc    = (u16*)(ws + 55050240);       // 2048x2048    8,388,608 B (kn reuses)
    u16* kvdc   = (u16*)(ws + 63438848);       // 512x2048     2,097,152 B
    u16* kupc   = (u16*)(ws + 65536000);       // 1024x512     1,048,576 B
    u16* kropec = (u16*)(ws + 66584576);       // 64x2048        262,144 B
    u16* vupc   = (u16*)(ws + 66846720);       // 2048x512     2,097,152 B
    u16* woc    = (u16*)(ws + 68943872);       // 2048x2048    8,388,608 B
    u16* attn   = xc;    // xc dead after the 3 projections
    u16* kn     = wqc;   // wqc dead after q gemm

    // 1) canonicalize all fp32 inputs to bf16 workspace copies
    struct { const void* src; u16* dst; int n; } conv[7] = {
        { d_in[0], xc,     4096*2048 },
        { d_in[1], wqc,    2048*2048 },
        { d_in[2], kvdc,    512*2048 },
        { d_in[3], kupc,   1024*512  },
        { d_in[4], kropec,   64*2048 },
        { d_in[5], vupc,   2048*512  },
        { d_in[6], woc,    2048*2048 },
    };
    for (int i = 0; i < 7; ++i) {
        int n8 = conv[i].n / 8;
        convert_in<<<(n8 + 255)/256, 256, 0, stream>>>((const float*)conv[i].src,
                                                       conv[i].dst, n8);
    }

    // 2) projections (bf16 out)
    gemm_bt<128,128><<<dim3(16, 32), 256, 0, stream>>>(xc, wqc, q, 4096, 2048, 2048);
    gemm_bt<128,128><<<dim3(4, 32), 256, 0, stream>>>(xc, kvdc, ckv, 4096, 512, 2048);
    gemm_bt<128,64><<<dim3(1, 32), 128, 0, stream>>>(xc, kropec, kr, 4096, 64, 2048);

    // 3) RoPE: q rope-half (rows=(b*S+s)*16+h, stride 128, cols 64..127); kr full
    rope_kernel<<<(2097152 + 255)/256, 256, 0, stream>>>(q, 2097152, 128, 64, 16);
    rope_kernel<<<(131072 + 255)/256, 256, 0, stream>>>(kr, 131072, 64, 0, 1);

    // 4) up-projections
    gemm_bt<128,128><<<dim3(8, 32), 256, 0, stream>>>(ckv, kupc, kn, 4096, 1024, 512);
    gemm_bt<128,128><<<dim3(16, 32), 256, 0, stream>>>(ckv, vupc, v, 4096, 2048, 512);

    // 5) attention: grid (32 q-tiles of 64, b*h), qt reversed in-kernel
    attn_kernel<<<dim3(32, 32), 256, 0, stream>>>(q, kn, kr, v, attn);

    // 6) output projection -> fp32 directly into d_out
    gemm_bt<128,128><<<dim3(16, 32), 256, 0, stream>>>(attn, woc, out, 4096, 2048, 2048);
}

// Round 7
// 476.552 us; speedup vs baseline: 1.4121x; 1.1893x over previous
//
#include <hip/hip_runtime.h>
#include <stdint.h>

// ---------------------------------------------------------------------------
// MLA attention, MI355X gfx950.
// Shapes: B=2 S=2048 D=2048 H=16 HD=128 ND=64 RD=64 R=512
// ABI: all 7 inputs fp32, output fp32. Internal: bf16 + fp32 accum.
//
// v4 layout plan:
//   qcat  [4096][2688] : cols 0..2047 q (rope'd in place; attn overwrites
//                        with its output), 2048..2111 kr (pre-rope),
//                        2112..2623 c_kv, 2624..2687 pad.
//   k_eff [4096][16][128] : per (s,h): [k_nope(64) | rope'd k_rope(64)]
//   vT    [2048][4096]    : v transposed (feature-major) via swapped GEMM
// ---------------------------------------------------------------------------

typedef unsigned short u16;
typedef __bf16 bf16x8 __attribute__((ext_vector_type(8)));
typedef float f32x4 __attribute__((ext_vector_type(4)));

__device__ __forceinline__ float bf2f(u16 u) {
    union { unsigned int i; float f; } x; x.i = ((unsigned int)u) << 16; return x.f;
}
__device__ __forceinline__ u16 f2bf(float f) {
    union { float f; unsigned int i; } x; x.f = f;
    unsigned int r = x.i + 0x7fffu + ((x.i >> 16) & 1u);   // RNE, finite inputs only
    return (u16)(r >> 16);
}
__device__ __forceinline__ void store_c(u16* p, float v)  { *p = f2bf(v); }
__device__ __forceinline__ void store_c(float* p, float v){ *p = v; }

#define GLOBAL_AS __attribute__((address_space(1)))
#define LDS_AS    __attribute__((address_space(3)))
__device__ __forceinline__ void gl_lds16(const void* g, void* l) {
    __builtin_amdgcn_global_load_lds((GLOBAL_AS const void*)g, (LDS_AS void*)l, 16, 0, 0);
}

// ---------------------------------------------------------------------------
// fp32 -> bf16 conversion, 8 elements/thread.
// ---------------------------------------------------------------------------
__global__ void convert_in(const float* __restrict__ src, u16* __restrict__ dst,
                           int n8) {
    int i = blockIdx.x * 256 + threadIdx.x;
    if (i >= n8) return;
    const float4* s = (const float4*)src;
    float4 v0 = s[2*i], v1 = s[2*i + 1];
    union { u16 u[8]; uint4 v; } o;
    o.u[0] = f2bf(v0.x); o.u[1] = f2bf(v0.y); o.u[2] = f2bf(v0.z); o.u[3] = f2bf(v0.w);
    o.u[4] = f2bf(v1.x); o.u[5] = f2bf(v1.y); o.u[6] = f2bf(v1.z); o.u[7] = f2bf(v1.w);
    *((uint4*)(dst + 8*i)) = o.v;
}

// ---------------------------------------------------------------------------
// GEMM: C[m][n] = sum_k A[m][k] * W[n][k]  (row-major, bf16, strides in elems)
// m97-style: BK=32, wave = 64x64 via 4x4 grid of 16x16x32 MFMA,
// global_load_lds width-16 staging. M%BM==0, N%BN==0, K%32==0.
// EPI: 0 = C[gm*ldc+gn]; 1 = k_eff column remap gn -> (gn>>6)*128+(gn&63).
// ---------------------------------------------------------------------------
template<int BM, int BN, int EPI, typename CT>
__global__ __launch_bounds__((BM/64)*(BN/64)*64)
void gemm_bt(const u16* __restrict__ A, const u16* __restrict__ W,
             CT* __restrict__ C, int M, int N, int K,
             int lda, int ldw, int ldc) {
    constexpr int BK = 32;
    constexpr int NWAVE = (BM/64)*(BN/64);
    constexpr int NT = NWAVE * 64;
    __shared__ u16 As[BM*BK];
    __shared__ u16 Bs[BN*BK];
    const int tid  = threadIdx.x;
    const int lane = tid & 63, l15 = lane & 15, quad = lane >> 4;
    const int wave = tid >> 6;
    const int wm = wave % (BM/64);
    const int wn = wave / (BM/64);
    const int bm = blockIdx.y * BM;
    const int bn = blockIdx.x * BN;

    const f32x4 fzero = {0.f, 0.f, 0.f, 0.f};
    f32x4 acc[4][4];
    #pragma unroll
    for (int i = 0; i < 4; ++i)
        #pragma unroll
        for (int j = 0; j < 4; ++j) acc[i][j] = fzero;

    const size_t Ab = (size_t)lda * 2;   // A row stride, bytes
    const size_t Wb = (size_t)ldw * 2;   // W row stride, bytes

    for (int k0 = 0; k0 < K; k0 += BK) {
        #pragma unroll
        for (int i = 0; i < (BM*64)/(NT*16); ++i) {
            int o = (tid + i*NT) * 16;
            int row = o >> 6, colb = o & 63;
            gl_lds16((const char*)A + (size_t)(bm + row)*Ab + (size_t)k0*2 + colb,
                     (char*)As + o);
        }
        #pragma unroll
        for (int i = 0; i < (BN*64)/(NT*16); ++i) {
            int o = (tid + i*NT) * 16;
            int row = o >> 6, colb = o & 63;
            gl_lds16((const char*)W + (size_t)(bn + row)*Wb + (size_t)k0*2 + colb,
                     (char*)Bs + o);
        }
        __syncthreads();

        bf16x8 af[4], bfv[4];
        #pragma unroll
        for (int mt = 0; mt < 4; ++mt)
            af[mt] = *reinterpret_cast<const bf16x8*>(&As[(wm*64 + mt*16 + l15)*BK + quad*8]);
        #pragma unroll
        for (int nt = 0; nt < 4; ++nt)
            bfv[nt] = *reinterpret_cast<const bf16x8*>(&Bs[(wn*64 + nt*16 + l15)*BK + quad*8]);
        #pragma unroll
        for (int mt = 0; mt < 4; ++mt)
            #pragma unroll
            for (int nt = 0; nt < 4; ++nt)
                acc[mt][nt] = __builtin_amdgcn_mfma_f32_16x16x32_bf16(
                    af[mt], bfv[nt], acc[mt][nt], 0, 0, 0);
        __syncthreads();
    }

    // epilogue: C/D layout col=lane&15, row=quad*4+reg (m89/m91 verified)
    #pragma unroll
    for (int mt = 0; mt < 4; ++mt)
        #pragma unroll
        for (int nt = 0; nt < 4; ++nt)
            #pragma unroll
            for (int r = 0; r < 4; ++r) {
                int gm = bm + wm*64 + mt*16 + quad*4 + r;
                int gn = bn + wn*64 + nt*16 + l15;
                size_t ci;
                if (EPI == 1) ci = (size_t)gm*ldc + ((gn >> 6)*128 + (gn & 63));
                else          ci = (size_t)gm*ldc + gn;
                store_c(&C[ci], acc[mt][nt][r]);
            }
}

// ---------------------------------------------------------------------------
// RoPE on q inside qcat: rows r=b*S+s (4096), per h: cols h*128+64 .. +127.
// idx: i=idx&31 (pair), h=(idx>>5)&15, r=idx>>9. pos = r & 2047.
// ---------------------------------------------------------------------------
__global__ void rope_q(u16* __restrict__ qcat) {
    int idx = blockIdx.x * 256 + threadIdx.x;   // 2,097,152 total
    int i = idx & 31, h = (idx >> 5) & 15, r = idx >> 9;
    int pos = r & 2047;
    float freq = powf(10000.0f, -(float)i * (1.0f/32.0f));
    float ang  = (float)pos * freq;
    float s = sinf(ang), c = cosf(ang);
    u16* p = qcat + (size_t)r * 2688 + h*128 + 64 + 2*i;
    float x0 = bf2f(p[0]), x1 = bf2f(p[1]);
    p[0] = f2bf(x0*c - x1*s);
    p[1] = f2bf(x1*c + x0*s);
}

// ---------------------------------------------------------------------------
// RoPE k_rope (qcat cols 2048..2111) and broadcast to k_eff cols 64..127 of
// all 16 heads. idx: i=idx&31, r=idx>>5. pos = r & 2047.
// ---------------------------------------------------------------------------
__global__ void rope_kr_bcast(const u16* __restrict__ qcat, u16* __restrict__ keff) {
    int idx = blockIdx.x * 256 + threadIdx.x;   // 131,072 total
    int i = idx & 31, r = idx >> 5;
    int pos = r & 2047;
    float freq = powf(10000.0f, -(float)i * (1.0f/32.0f));
    float ang  = (float)pos * freq;
    float s = sinf(ang), c = cosf(ang);
    const u16* p = qcat + (size_t)r * 2688 + 2048 + 2*i;
    float x0 = bf2f(p[0]), x1 = bf2f(p[1]);
    union { u16 u[2]; unsigned int w; } o;
    o.u[0] = f2bf(x0*c - x1*s);
    o.u[1] = f2bf(x1*c + x0*s);
    unsigned int* base = (unsigned int*)(keff + (size_t)r*2048 + 64 + 2*i);
    #pragma unroll
    for (int h = 0; h < 16; ++h) base[h*64] = o.w;   // 128 u16 = 64 u32 stride
}

// ---------------------------------------------------------------------------
// Flash-style causal attention, v4: coalesced staging layouts.
// grid = (32 q-tiles of 64, B*H), qt reversed. block = 256 (4 waves);
// wave owns 16 q-rows. LDS 40.7 KB -> 3 blocks/CU.
// K from k_eff[s][h][128] (256B rows), V from vT[feat][s] (128B row spans) —
// XOR swizzles folded into the GLOBAL source so LDS stays linear and both
// QK and PV B-frag ds_read_b128 are conflict-free (2-way max).
// Register prefetch of tile kt+1 during compute of kt (v3 pipeline).
// Output written IN PLACE over the Q columns of qcat (same block's rows).
// ---------------------------------------------------------------------------
__global__ __launch_bounds__(256, 3)
void attn_kernel(u16* __restrict__ qcat, const u16* __restrict__ KE,
                 const u16* __restrict__ VT) {
    constexpr int S = 2048;
    const int qt = 31 - (int)blockIdx.x;     // reversed: long blocks first
    const int bh = blockIdx.y;
    const int b = bh >> 4, h = bh & 15;

    __shared__ u16 Ks[64*128];     // K tile, chunk-swizzled by (row&15), 16 KB
    __shared__ u16 Vs[128*64];     // V^T tile, chunk-swizzled by (d&7), 16 KB
    __shared__ u16 Ps[64*68];      // P, row stride 68, 8.7 KB

    const int tid  = threadIdx.x;
    const int lane = tid & 63, l15 = lane & 15, quad = lane >> 4;
    const int wave = tid >> 6;

    // Q A-frags in registers: A[m=l15][k=quad*8+j], 4 k-steps of 32
    u16* qbase = qcat + (size_t)(b*S + qt*64) * 2688 + h*128;
    bf16x8 aq[4];
    #pragma unroll
    for (int ks = 0; ks < 4; ++ks)
        aq[ks] = *reinterpret_cast<const bf16x8*>(
            qbase + (size_t)(wave*16 + l15)*2688 + ks*32 + quad*8);

    // staging sources (swizzle folded into global address)
    const u16* ksrc[4];
    const u16* vsrc[4];
    #pragma unroll
    for (int i = 0; i < 4; ++i) {
        int g = tid + i*256;
        { // K: 64 rows x 256B; chunk slot (g&15) holds logical chunk slot^(row&15)
            int r = g >> 4, slot = g & 15, cg = slot ^ (r & 15);
            ksrc[i] = KE + (size_t)(b*S + r)*2048 + h*128 + cg*8;
        }
        { // V: 128 rows x 128B; chunk slot (g&7) holds logical chunk slot^(d&7)
            int d = g >> 3, slot = g & 7, cg = slot ^ (d & 7);
            vsrc[i] = VT + (size_t)(h*128 + d)*4096 + (size_t)(b*S) + cg*8;
        }
    }
    const int nkt = qt + 1;

    // prefetch tile 0
    bf16x8 kreg[4], vreg[4];
    #pragma unroll
    for (int i = 0; i < 4; ++i) {
        kreg[i] = *reinterpret_cast<const bf16x8*>(ksrc[i]);
        vreg[i] = *reinterpret_cast<const bf16x8*>(vsrc[i]);
    }

    const f32x4 fzero = {0.f, 0.f, 0.f, 0.f};
    const float NEG = -1e30f;
    float m_i[4] = {NEG, NEG, NEG, NEG};
    float l_i[4] = {0.f, 0.f, 0.f, 0.f};
    f32x4 oacc[8];
    #pragma unroll
    for (int i = 0; i < 8; ++i) oacc[i] = fzero;

    const float scale = 0.08838834764831845f;   // 1/sqrt(128)
    const int qrow0 = qt*64 + wave*16 + quad*4;

    for (int kt = 0; kt < nkt; ++kt) {
        // dump prefetched tile kt to LDS (vector writes, linear layout)
        #pragma unroll
        for (int i = 0; i < 4; ++i) {
            *reinterpret_cast<bf16x8*>(&Ks[(tid + i*256) * 8]) = kreg[i];
            *reinterpret_cast<bf16x8*>(&Vs[(tid + i*256) * 8]) = vreg[i];
        }
        // prefetch tile kt+1 (clamped on last iteration)
        {
            int ktn = (kt + 1 < nkt) ? kt + 1 : kt;
            #pragma unroll
            for (int i = 0; i < 4; ++i) {
                kreg[i] = *reinterpret_cast<const bf16x8*>(ksrc[i] + (size_t)ktn*(64*2048));
                vreg[i] = *reinterpret_cast<const bf16x8*>(vsrc[i] + (size_t)ktn*64);
            }
        }
        __syncthreads();

        // S = Q K^T (16 q-rows x 64 kv-cols per wave)
        f32x4 sfr[4];
        #pragma unroll
        for (int nt = 0; nt < 4; ++nt) {
            f32x4 s = fzero;
            int n = nt*16 + l15;
            #pragma unroll
            for (int ks = 0; ks < 4; ++ks) {
                int c = ks*4 + quad;
                bf16x8 bk = *reinterpret_cast<const bf16x8*>(&Ks[n*128 + ((c ^ l15) * 8)]);
                s = __builtin_amdgcn_mfma_f32_16x16x32_bf16(aq[ks], bk, s, 0, 0, 0);
            }
            sfr[nt] = s;
        }
        // scale + causal mask
        #pragma unroll
        for (int nt = 0; nt < 4; ++nt) {
            int kg = kt*64 + nt*16 + l15;
            #pragma unroll
            for (int r = 0; r < 4; ++r) {
                float v = sfr[nt][r] * scale;
                sfr[nt][r] = (kg <= qrow0 + r) ? v : NEG;
            }
        }
        // online softmax
        float rm[4];
        #pragma unroll
        for (int r = 0; r < 4; ++r)
            rm[r] = fmaxf(fmaxf(sfr[0][r], sfr[1][r]), fmaxf(sfr[2][r], sfr[3][r]));
        #pragma unroll
        for (int off = 1; off < 16; off <<= 1)
            #pragma unroll
            for (int r = 0; r < 4; ++r)
                rm[r] = fmaxf(rm[r], __shfl_xor(rm[r], off, 64));

        float alpha[4];
        #pragma unroll
        for (int r = 0; r < 4; ++r) {
            float mn = fmaxf(m_i[r], rm[r]);
            alpha[r] = __expf(m_i[r] - mn);
            m_i[r] = mn;
            l_i[r] *= alpha[r];
        }
        float rs[4] = {0.f, 0.f, 0.f, 0.f};
        float pf[4][4];
        #pragma unroll
        for (int nt = 0; nt < 4; ++nt)
            #pragma unroll
            for (int r = 0; r < 4; ++r) {
                float p = __expf(sfr[nt][r] - m_i[r]);
                pf[nt][r] = p;
                rs[r] += p;
            }
        #pragma unroll
        for (int off = 1; off < 16; off <<= 1)
            #pragma unroll
            for (int r = 0; r < 4; ++r)
                rs[r] += __shfl_xor(rs[r], off, 64);
        #pragma unroll
        for (int r = 0; r < 4; ++r) l_i[r] += rs[r];
        #pragma unroll
        for (int i = 0; i < 8; ++i)
            #pragma unroll
            for (int r = 0; r < 4; ++r)
                oacc[i][r] *= alpha[r];

        // P: C-layout -> LDS (wave-private rows, stride 68)
        #pragma unroll
        for (int nt = 0; nt < 4; ++nt)
            #pragma unroll
            for (int r = 0; r < 4; ++r)
                Ps[(wave*16 + quad*4 + r)*68 + nt*16 + l15] = f2bf(pf[nt][r]);

        // O += P V: A-frags from Ps, B-frags from swizzled Vs
        #pragma unroll
        for (int ks = 0; ks < 2; ++ks) {
            bf16x8 pa = *reinterpret_cast<const bf16x8*>(
                &Ps[(wave*16 + l15)*68 + ks*32 + quad*8]);
            #pragma unroll
            for (int ntv = 0; ntv < 8; ++ntv) {
                int c = ks*4 + quad;
                bf16x8 bv = *reinterpret_cast<const bf16x8*>(
                    &Vs[(ntv*16 + l15)*64 + ((c ^ (l15 & 7)) * 8)]);
                oacc[ntv] = __builtin_amdgcn_mfma_f32_16x16x32_bf16(pa, bv, oacc[ntv], 0, 0, 0);
            }
        }
        __syncthreads();
    }

    // epilogue: normalize, write IN PLACE over this block's own Q rows
    #pragma unroll
    for (int r = 0; r < 4; ++r) {
        float inv = 1.0f / l_i[r];
        int qrow = wave*16 + quad*4 + r;
        #pragma unroll
        for (int ntv = 0; ntv < 8; ++ntv) {
            int d = ntv*16 + l15;
            qbase[(size_t)qrow*2688 + d] = f2bf(oacc[ntv][r] * inv);
        }
    }
}

// ---------------------------------------------------------------------------
// Host launcher. Inputs fp32, output fp32.
// ---------------------------------------------------------------------------
extern "C" void kernel_launch(void* const* d_in, const int* in_sizes, int n_in,
                              void* d_out, int out_size, void* d_ws, size_t ws_size,
                              hipStream_t stream) {
    (void)in_sizes; (void)n_in; (void)out_size; (void)ws_size;
    float* out = (float*)d_out;
    char* ws = (char*)d_ws;

    // workspace (bytes), total 69,730,304 (< proven 77.3 MB)
    u16* xc     = (u16*)(ws);                  // 4096x2048   16,777,216  (vT reuses)
    u16* qcat   = (u16*)(ws + 16777216);       // 4096x2688   22,020,096
    u16* keff   = (u16*)(ws + 38797312);       // 4096x2048   16,777,216
    u16* wqcat  = (u16*)(ws + 55574528);       // 2688x2048   11,010,048  (woc reuses)
    u16* kupc   = (u16*)(ws + 66584576);       // 1024x512     1,048,576
    u16* vupc   = (u16*)(ws + 67633152);       // 2048x512     2,097,152
    u16* vT     = xc;      // xc dead after projection GEMM
    u16* woc    = wqcat;   // wqcat dead after projection GEMM

    // 1) convert fp32 inputs to bf16 (wq | w_k_rope | w_kv_down concatenated)
    //    n8 = element_count / 8  (R6 bug: x used n/4 -> OOB; fixed to 1048576)
    convert_in<<<(1048576+255)/256, 256, 0, stream>>>((const float*)d_in[0], xc, 1048576);              // x 4096x2048
    convert_in<<<( 524288+255)/256, 256, 0, stream>>>((const float*)d_in[1], wqcat, 524288);            // wq rows 0..2047
    convert_in<<<(  16384+255)/256, 256, 0, stream>>>((const float*)d_in[4], wqcat + 2048*2048, 16384); // w_k_rope rows 2048..2111
    convert_in<<<( 131072+255)/256, 256, 0, stream>>>((const float*)d_in[2], wqcat + 2112*2048, 131072);// w_kv_down rows 2112..2623
    convert_in<<<(  65536+255)/256, 256, 0, stream>>>((const float*)d_in[3], kupc, 65536);              // w_k_up
    convert_in<<<( 131072+255)/256, 256, 0, stream>>>((const float*)d_in[5], vupc, 131072);             // w_v_up

    // 2) fat projection: qcat = xc @ wqcat^T   (N=2688 incl. 64 pad cols)
    gemm_bt<128,128,0><<<dim3(21, 32), 256, 0, stream>>>(
        xc, wqcat, qcat, 4096, 2688, 2048, 2048, 2048, 2688);

    // 3) convert wo into the now-dead wqcat region
    convert_in<<<(524288+255)/256, 256, 0, stream>>>((const float*)d_in[6], woc, 524288);

    // 4) RoPE q (in qcat) and rope+broadcast k_rope into k_eff cols 64..127
    rope_q<<<8192, 256, 0, stream>>>(qcat);
    rope_kr_bcast<<<512, 256, 0, stream>>>(qcat, keff);

    // 5) k_up: k_nope into k_eff cols (h*128..h*128+63) via remap epilogue
    gemm_bt<128,128,1><<<dim3(8, 32), 256, 0, stream>>>(
        qcat + 2112, kupc, keff, 4096, 1024, 512, 2688, 512, 2048);

    // 6) v_up TRANSPOSED via operand swap: vT[feat][s] = w_v_up @ c_kv^T
    gemm_bt<128,128,0><<<dim3(32, 16), 256, 0, stream>>>(
        vupc, qcat + 2112, vT, 2048, 4096, 512, 512, 2688, 4096);

    // 7) attention (in-place output into qcat q-columns)
    attn_kernel<<<dim3(32, 32), 256, 0, stream>>>(qcat, keff, vT);

    // 8) output projection -> fp32 d_out
    gemm_bt<128,128,0><<<dim3(16, 32), 256, 0, stream>>>(
        qcat, woc, out, 4096, 2048, 2048, 2688, 2048, 2048);
}